// Round 6
// baseline (61.169 us; speedup 1.0000x reference)
//
#include <hip/hip_runtime.h>

// SSIM loss: predict/gt (32,1,512,512) f32, 11-tap separable gaussian (sigma=1.5),
// VALID padding -> 502x502 per image, loss = 1 - mean(ssim_map).
//
// Round 6: same streaming-column structure (zero LDS data path), but 2x wave
// supply for latency hiding: 32-row strips, 1024 blocks -> 16 waves/CU.
// Single fdividef per output.

constexpr int WIN = 11;
constexpr int H = 512, W = 512, NIMG = 32;
constexpr int OH = H - WIN + 1, OW = W - WIN + 1;  // 502
constexpr int RPS = 32;                   // output rows per strip
constexpr int NSTRIP = 16;                // 16*32 = 512 >= 502
constexpr int NBLK = NIMG * NSTRIP * 2;   // 1024 blocks
constexpr float C1 = 0.009801f;   // (0.01*9.9)^2
constexpr float C2 = 0.088209f;   // (0.03*9.9)^2
constexpr double TOTAL = (double)NIMG * (double)OH * (double)OW;

// gaussian weights, sigma=1.5, normalized
__device__ constexpr float WGT[WIN] = {
    0.0010285f, 0.0075988f, 0.0360008f, 0.1093607f, 0.2130054f,
    0.2660118f,
    0.2130054f, 0.1093607f, 0.0360008f, 0.0075988f, 0.0010285f};

template <int U>
__device__ __forceinline__ void row_body(int base, int r0,
                                         const float* __restrict__ p,
                                         const float* __restrict__ g,
                                         float (&hp)[WIN], float (&hg)[WIN],
                                         float (&hpp)[WIN], float (&hgg)[WIN],
                                         float (&hpg)[WIN],
                                         bool active, float& lsum) {
    const int rin = base + U;
    const int rr = min(rin, H - 1);          // clamp (tail strip only)
    const float* rp = p + (size_t)rr * W;
    const float* rg = g + (size_t)rr * W;

    // horizontal 11-tap conv of p, g, p*p, g*g, p*g
    float a0 = 0.f, a1 = 0.f, a2 = 0.f, a3 = 0.f, a4 = 0.f;
#pragma unroll
    for (int k = 0; k < WIN; ++k) {
        const float pv = rp[k];
        const float gv = rg[k];
        const float w = WGT[k];
        const float wp = w * pv;
        a0 = fmaf(w, pv, a0);
        a1 = fmaf(w, gv, a1);
        a2 = fmaf(wp, pv, a2);
        a4 = fmaf(wp, gv, a4);
        a3 = fmaf(w * gv, gv, a3);
    }
    hp[U] = a0; hg[U] = a1; hpp[U] = a2; hgg[U] = a3; hpg[U] = a4;

    // vertical conv + SSIM for output row rin-10 (ring slots static after unroll)
    const int ro = rin - (WIN - 1);
    if (ro >= r0 && ro < OH) {               // wave-uniform branch
        float m1 = 0.f, m2 = 0.f, e11 = 0.f, e22 = 0.f, e12 = 0.f;
#pragma unroll
        for (int k = 0; k < WIN; ++k) {
            const int s = (U + 1 + k) % WIN;
            const float w = WGT[k];
            m1  = fmaf(w, hp[s], m1);
            m2  = fmaf(w, hg[s], m2);
            e11 = fmaf(w, hpp[s], e11);
            e22 = fmaf(w, hgg[s], e22);
            e12 = fmaf(w, hpg[s], e12);
        }
        const float mu11 = m1 * m1, mu22 = m2 * m2, mu12 = m1 * m2;
        const float s11 = e11 - mu11, s22 = e22 - mu22, s12 = e12 - mu12;
        const float num = (2.f * mu12 + C1) * (2.f * s12 + C2);
        const float den = (mu11 + mu22 + C1) * (s11 + s22 + C2);
        const float ssim = __fdividef(num, den);
        lsum += active ? ssim : 0.f;
    }
}

__global__ __launch_bounds__(256) void ssim_stream_kernel(const float* __restrict__ P,
                                                          const float* __restrict__ G,
                                                          float* __restrict__ blocksum) {
    const int tid = threadIdx.x;
    const int bid = blockIdx.x;
    const int img = bid >> 5;          // 32 blocks per image (16 strips x 2 col-halves)
    const int sb = bid & 31;
    const int strip = sb >> 1;
    const int cb = sb & 1;

    int col = cb * 256 + tid;          // 0..511
    const bool active = col < OW;      // 502
    if (!active) col = OW - 1;         // clamp: duplicate compute, masked from sum

    const int r0 = strip * RPS;        // first output row of this strip

    const float* p = P + (size_t)img * H * W + col;
    const float* g = G + (size_t)img * H * W + col;

    float hp[WIN], hg[WIN], hpp[WIN], hgg[WIN], hpg[WIN];
    float lsum = 0.f;

    // 42 input rows: 3 x 11 + 9 (ring slot = i % 11, static via unroll)
    int base = r0;
#pragma unroll 1
    for (int ii = 0; ii < 3; ++ii, base += 11) {
        row_body<0>(base, r0, p, g, hp, hg, hpp, hgg, hpg, active, lsum);
        row_body<1>(base, r0, p, g, hp, hg, hpp, hgg, hpg, active, lsum);
        row_body<2>(base, r0, p, g, hp, hg, hpp, hgg, hpg, active, lsum);
        row_body<3>(base, r0, p, g, hp, hg, hpp, hgg, hpg, active, lsum);
        row_body<4>(base, r0, p, g, hp, hg, hpp, hgg, hpg, active, lsum);
        row_body<5>(base, r0, p, g, hp, hg, hpp, hgg, hpg, active, lsum);
        row_body<6>(base, r0, p, g, hp, hg, hpp, hgg, hpg, active, lsum);
        row_body<7>(base, r0, p, g, hp, hg, hpp, hgg, hpg, active, lsum);
        row_body<8>(base, r0, p, g, hp, hg, hpp, hgg, hpg, active, lsum);
        row_body<9>(base, r0, p, g, hp, hg, hpp, hgg, hpg, active, lsum);
        row_body<10>(base, r0, p, g, hp, hg, hpp, hgg, hpg, active, lsum);
    }
    // epilogue rows i = 33..41 (slots 0..8)
    row_body<0>(base, r0, p, g, hp, hg, hpp, hgg, hpg, active, lsum);
    row_body<1>(base, r0, p, g, hp, hg, hpp, hgg, hpg, active, lsum);
    row_body<2>(base, r0, p, g, hp, hg, hpp, hgg, hpg, active, lsum);
    row_body<3>(base, r0, p, g, hp, hg, hpp, hgg, hpg, active, lsum);
    row_body<4>(base, r0, p, g, hp, hg, hpp, hgg, hpg, active, lsum);
    row_body<5>(base, r0, p, g, hp, hg, hpp, hgg, hpg, active, lsum);
    row_body<6>(base, r0, p, g, hp, hg, hpp, hgg, hpg, active, lsum);
    row_body<7>(base, r0, p, g, hp, hg, hpp, hgg, hpg, active, lsum);
    row_body<8>(base, r0, p, g, hp, hg, hpp, hgg, hpg, active, lsum);

    // block reduction: wave64 shuffle, then cross-wave via LDS; plain store
#pragma unroll
    for (int off = 32; off > 0; off >>= 1)
        lsum += __shfl_down(lsum, off, 64);

    __shared__ float wsum[4];
    const int wid = tid >> 6, lane = tid & 63;
    if (lane == 0) wsum[wid] = lsum;
    __syncthreads();
    if (tid == 0) {
        blocksum[bid] = (wsum[0] + wsum[1]) + (wsum[2] + wsum[3]);
    }
}

// one-block reduction of 1024 block sums -> loss scalar
__global__ __launch_bounds__(256) void reduce_kernel(const float* __restrict__ blocksum,
                                                     float* __restrict__ out) {
    const int tid = threadIdx.x;
    const float4 v = ((const float4*)blocksum)[tid];
    float s = (v.x + v.y) + (v.z + v.w);
#pragma unroll
    for (int off = 32; off > 0; off >>= 1)
        s += __shfl_down(s, off, 64);

    __shared__ float wsum[4];
    const int wid = tid >> 6, lane = tid & 63;
    if (lane == 0) wsum[wid] = s;
    __syncthreads();
    if (tid == 0) {
        const float total = (wsum[0] + wsum[1]) + (wsum[2] + wsum[3]);
        out[0] = 1.f - total * (float)(1.0 / TOTAL);
    }
}

extern "C" void kernel_launch(void* const* d_in, const int* in_sizes, int n_in,
                              void* d_out, int out_size, void* d_ws, size_t ws_size,
                              hipStream_t stream) {
    const float* P = (const float*)d_in[0];   // predict
    const float* G = (const float*)d_in[1];   // gt
    float* out = (float*)d_out;
    float* blocksum = (float*)d_ws;           // NBLK floats

    ssim_stream_kernel<<<NBLK, 256, 0, stream>>>(P, G, blocksum);
    reduce_kernel<<<1, 256, 0, stream>>>(blocksum, out);
}